// Round 17
// baseline (4714.079 us; speedup 1.0000x reference)
//
#include <hip/hip_runtime.h>
#include <hip/hip_bf16.h>
#include <math.h>

typedef __attribute__((ext_vector_type(8))) short bf16x8;
typedef __attribute__((ext_vector_type(4))) float f32x4;
typedef __attribute__((ext_vector_type(4))) unsigned short u16x4;

#define B_   16
#define C_   128
#define CHW_ 131072   // 128*32*32
#define STR_ 138      // ZT pixel stride in shorts (69 dwords, odd -> bank spread)
#define TH_  34       // tmp halo dim: [img][34][34][128], border ring = zeros

__device__ __forceinline__ unsigned short f2bf(float f) {
  union { float f; unsigned int i; } v; v.f = f;
  unsigned int lsb = (v.i >> 16) & 1u;
  v.i += 0x7fffu + lsb;
  return (unsigned short)(v.i >> 16);
}

// fast tanh: 1 - 2/(e^{2x}+1). Saturates correctly at +/-inf.
__device__ __forceinline__ float fast_tanh(float x) {
  float e = __expf(2.f * x);
  return 1.f - 2.f * __builtin_amdgcn_rcpf(e + 1.f);
}

// ---- weight prep: W[O][I][3][3] f32 -> wpk[ks][co][ci&31] bf16, ks = off*4 + (ci>>5)
__global__ void prep_weights(const float* __restrict__ W1, const float* __restrict__ W2,
                             unsigned short* __restrict__ w1bf, unsigned short* __restrict__ w2bf) {
  int j = blockIdx.x * 256 + threadIdx.x;
  if (j >= 2 * 147456) return;
  int which = j / 147456;
  int r = j - which * 147456;
  int ks = r >> 12;
  int co = (r >> 5) & 127;
  int c5 = r & 31;
  int off = ks >> 2;
  int ci  = (ks & 3) * 32 + c5;
  const float* src = which ? W2 : W1;
  unsigned short* dst = which ? w2bf : w1bf;
  dst[r] = f2bf(src[(co * 128 + ci) * 9 + off]);
}

// ---- init: y32 = y0 (NCHW f32); dout[:,t=0,...] = y0
__global__ void init_copy(const float* __restrict__ y0, float* __restrict__ y32,
                          float* __restrict__ dout) {
  int i = blockIdx.x * 256 + threadIdx.x;
  if (i >= B_ * CHW_) return;
  float v = y0[i];
  y32[i] = v;
  int b = i >> 17, chw = i & (CHW_ - 1);
  dout[b * 25 * CHW_ + chw] = v;
}

// ---- init: tmpH (zero-halo NHWC bf16) interior = transpose(y0)
__global__ void init_transpose(const float* __restrict__ y0, unsigned short* __restrict__ tmpH) {
  __shared__ float t[32][33];
  int blk = blockIdx.x;          // 16 b * 4 co-tiles * 32 pix-tiles = 2048
  int b = blk >> 7;
  int rem = blk & 127;
  int co0 = (rem >> 5) * 32;
  int p0  = (rem & 31) * 32;
  int tx = threadIdx.x & 31, ty = threadIdx.x >> 5;
  #pragma unroll
  for (int k = 0; k < 4; k++) {
    int cl = ty + k * 8;
    t[cl][tx] = y0[b * CHW_ + (co0 + cl) * 1024 + p0 + tx];
  }
  __syncthreads();
  #pragma unroll
  for (int k = 0; k < 4; k++) {
    int pl = ty + k * 8;
    int p = p0 + pl;
    int row = p >> 5, col = p & 31;
    tmpH[((b * TH_ + row + 1) * TH_ + col + 1) * 128 + co0 + tx] = f2bf(t[tx][pl]);
  }
}

// ---- fused RK4 stage kernel (multi-launch, plain cached loads).
// Round 17: conv1's B-operand read DIRECTLY from L2 (zero-halo NHWC tmp) --
// no IT staging tile, no first sync. LDS = ZT only (37.5 KB) -> 2 blocks/CU,
// 4 waves/SIMD; co-resident blocks cover different (img,rowpair) work.
// A-minimal wave partition (r15, proven): each wave owns ONE 16-co fragment
// and the whole spatial tile -> block A traffic = |W1|+|W2| = 576 KB.
// conv1 wave: 16co x 4 zrows x 32 cols, acc[4][2]; per (dw,kk): 3A + 12B(L2) -> 24 MFMA.
// conv2 wave: 16co x 2 rows  x 32 cols, acc[2][2]; per (dw,kk): 3A +  8B(LDS) -> 12 MFMA.
// Grid: 16 images x 16 rowpairs = 256 blocks, 512 thr (8 waves).
template<int ST>
__global__ __launch_bounds__(512, 4)
void fused_stage(const unsigned short* __restrict__ w1bf,
                 const unsigned short* __restrict__ w2bf,
                 const float* __restrict__ b1v, const float* __restrict__ b2v,
                 unsigned short* __restrict__ tmpH,
                 float* __restrict__ y32, float* __restrict__ acc32,
                 float* __restrict__ dout, const float* __restrict__ tarr, int step)
{
  // ZT: z tile, 4 rows (r0-1..r0+2) x 34 cols x 128 co (LDS-only)
  __shared__ unsigned short ZT[136 * STR_];
  const int tid  = threadIdx.x;
  const int img  = blockIdx.x >> 4;
  const int r0   = (blockIdx.x & 15) * 2;
  const int lane = tid & 63;
  const int wave = tid >> 6;          // = co-fragment index (0..7)
  const int lhi  = lane >> 4;         // 0..3 (K octet / D row group)
  const int llo  = lane & 15;         // A: co row, B: sp col, D: col

  const unsigned short* a1base = w1bf + (wave * 16 + llo) * 32 + lhi * 8;
  const unsigned short* a2base = w2bf + (wave * 16 + llo) * 32 + lhi * 8;
  // conv1 B base: halo rows r0-1+rr (rr=0..5), halo col = spt*16+llo+dw.
  // Edge over-reads (r0=0 rr=0 / r0=30 rr=5) land in adjacent ws regions --
  // mapped memory, garbage feeds only DEAD z-rows (masked at ZT write).
  const unsigned short* bbase = tmpH + (((long)img * TH_ + (r0 - 1)) * TH_ + llo) * 128 + lhi * 8;

  float t0 = tarr[step];
  float t1 = tarr[step + 1];
  // keep one operand in a VGPR: avoids V_ADD_F32 with two SGPR sources
  // (constant-bus violation -> backend compile error on gfx950)
  asm volatile("" : "+v"(t1));
  const float dt = t1 - t0;
  const float dt6 = dt * (1.f / 6.f), dt3 = dt * (1.f / 3.f), dth = dt * 0.5f;

  // ---- zero ZT col pads (structural zeros, each launch)
  if (tid < 128) {
    int zp  = tid >> 4;
    int oct = tid & 15;
    int zpix = (zp >> 1) * 34 + ((zp & 1) ? 33 : 0);
    bf16x8 z = {0, 0, 0, 0, 0, 0, 0, 0};
    *(bf16x8*)(ZT + zpix * STR_ + oct * 8) = z;
  }

  // ---- conv1: z = tanh(conv(tmp,W1)+b1), wave computes 16co x 4 zrows x 32 cols
  {
    const int co = wave * 16 + lhi * 4;
    f32x4 bia = *(const f32x4*)(b1v + co);
    f32x4 a1[4][2];   // [zr][spt]
    #pragma unroll
    for (int i = 0; i < 4; i++) { a1[i][0] = (f32x4){0,0,0,0}; a1[i][1] = (f32x4){0,0,0,0}; }
    #pragma unroll
    for (int dw = 0; dw < 3; ++dw) {
      #pragma unroll
      for (int kk = 0; kk < 4; ++kk) {
        bf16x8 afr[3];
        #pragma unroll
        for (int dh = 0; dh < 3; ++dh)
          afr[dh] = *(const bf16x8*)(a1base + ((dh * 3 + dw) * 4 + kk) * 4096);
        #pragma unroll
        for (int spt = 0; spt < 2; ++spt) {
          // 6 input rows (L2, coalesced: 16 lanes x consecutive pixels x 16B)
          bf16x8 bfr[6];
          #pragma unroll
          for (int rr = 0; rr < 6; ++rr)
            bfr[rr] = *(const bf16x8*)(bbase + ((long)rr * TH_ + spt * 16 + dw) * 128 + kk * 32);
          #pragma unroll
          for (int dh = 0; dh < 3; ++dh)
            #pragma unroll
            for (int zr = 0; zr < 4; ++zr)
              a1[zr][spt] = __builtin_amdgcn_mfma_f32_16x16x32_bf16(afr[dh], bfr[zr + dh], a1[zr][spt], 0, 0, 0);
        }
      }
    }
    #pragma unroll
    for (int zr = 0; zr < 4; ++zr) {
      const bool live = (unsigned)(r0 - 1 + zr) < 32u;
      #pragma unroll
      for (int spt = 0; spt < 2; ++spt) {
        const int c = spt * 16 + llo;
        u16x4 pk;
        #pragma unroll
        for (int reg = 0; reg < 4; ++reg)
          pk[reg] = live ? f2bf(fast_tanh(a1[zr][spt][reg] + bia[reg])) : (unsigned short)0;
        *(u16x4*)(ZT + (zr * 34 + c + 1) * STR_ + co) = pk;
      }
    }
  }
  __syncthreads();

  // ---- conv2: k = conv(z,W2)+b2, wave computes 16co x 2 rows x 32 cols + RK4
  {
    const int co0 = wave * 16 + lhi * 4;
    f32x4 bia = *(const f32x4*)(b2v + co0);
    // prefetch epilogue state BEFORE the K-loop: latency hides under 144 MFMAs
    float ypre[2][2][4], apre[2][2][4];
    #pragma unroll
    for (int q = 0; q < 2; ++q)
      #pragma unroll
      for (int spt = 0; spt < 2; ++spt) {
        const int idx0 = img * CHW_ + co0 * 1024 + (r0 + q) * 32 + spt * 16 + llo;
        #pragma unroll
        for (int reg = 0; reg < 4; ++reg) {
          if constexpr (ST <= 3) ypre[q][spt][reg] = y32[idx0 + reg * 1024];
          if constexpr (ST >= 2) apre[q][spt][reg] = acc32[idx0 + reg * 1024];
        }
      }

    f32x4 a2[2][2];   // [q(row)][spt]
    #pragma unroll
    for (int i = 0; i < 2; i++) { a2[i][0] = (f32x4){0,0,0,0}; a2[i][1] = (f32x4){0,0,0,0}; }
    #pragma unroll
    for (int dw = 0; dw < 3; ++dw) {
      #pragma unroll
      for (int kk = 0; kk < 4; ++kk) {
        bf16x8 afr[3];
        #pragma unroll
        for (int dh = 0; dh < 3; ++dh)
          afr[dh] = *(const bf16x8*)(a2base + ((dh * 3 + dw) * 4 + kk) * 4096);
        #pragma unroll
        for (int spt = 0; spt < 2; ++spt) {
          bf16x8 bfr[4];
          #pragma unroll
          for (int rr = 0; rr < 4; ++rr)
            bfr[rr] = *(const bf16x8*)(ZT + (rr * 34 + spt * 16 + llo + dw) * STR_ + kk * 32 + lhi * 8);
          #pragma unroll
          for (int dh = 0; dh < 3; ++dh)
            #pragma unroll
            for (int q = 0; q < 2; ++q)
              a2[q][spt] = __builtin_amdgcn_mfma_f32_16x16x32_bf16(afr[dh], bfr[q + dh], a2[q][spt], 0, 0, 0);
        }
      }
    }

    #pragma unroll
    for (int q = 0; q < 2; ++q) {
      const int row = r0 + q;
      #pragma unroll
      for (int spt = 0; spt < 2; ++spt) {
        const int col = spt * 16 + llo;
        const int phalo = (((long)img * TH_ + row + 1) * TH_ + col + 1) * 128 + co0;
        const int idx0  = img * CHW_ + co0 * 1024 + row * 32 + col;
        u16x4 pk;
        #pragma unroll
        for (int reg = 0; reg < 4; ++reg) {
          float kv = a2[q][spt][reg] + bia[reg];
          int id = idx0 + reg * 1024;
          float tv;
          if constexpr (ST == 1)      { float yv = ypre[q][spt][reg]; acc32[id] = yv + dt6 * kv; tv = yv + dth * kv; }
          else if constexpr (ST == 2) { float yv = ypre[q][spt][reg]; acc32[id] = apre[q][spt][reg] + dt3 * kv; tv = yv + dth * kv; }
          else if constexpr (ST == 3) { float yv = ypre[q][spt][reg]; acc32[id] = apre[q][spt][reg] + dt3 * kv; tv = yv + dt * kv; }
          else {
            tv = apre[q][spt][reg] + dt6 * kv;
            y32[id] = tv;
            dout[(img * 25 + step + 1) * CHW_ + co0 * 1024 + row * 32 + col + reg * 1024] = tv;
          }
          pk[reg] = f2bf(tv);
        }
        *(u16x4*)(tmpH + phalo) = pk;
      }
    }
  }
}

extern "C" void kernel_launch(void* const* d_in, const int* in_sizes, int n_in,
                              void* d_out, int out_size, void* d_ws, size_t ws_size,
                              hipStream_t stream) {
  const float* y0   = (const float*)d_in[0];
  const float* tarr = (const float*)d_in[1];
  const float* W1   = (const float*)d_in[2];
  const float* b1   = (const float*)d_in[3];
  const float* W2   = (const float*)d_in[4];
  const float* b2   = (const float*)d_in[5];
  float* dout = (float*)d_out;

  char* ws = (char*)d_ws;
  float* y32           = (float*)(ws);                          // 8 MB (NCHW)
  float* acc32         = (float*)(ws + (8u << 20));             // 8 MB (NCHW)
  unsigned short* tmpH = (unsigned short*)(ws + (16u << 20));   // 4.74 MB (zero-halo NHWC)
  unsigned short* w1bf = (unsigned short*)(ws + (22u << 20));   // 288 KB
  unsigned short* w2bf = (unsigned short*)(ws + (22u << 20) + 294912);

  const size_t tmpH_bytes = (size_t)B_ * TH_ * TH_ * 128 * 2;   // 4,734,976 B

  prep_weights<<<(2 * 147456 + 255) / 256, 256, 0, stream>>>(W1, W2, w1bf, w2bf);
  init_copy<<<(B_ * CHW_ + 255) / 256, 256, 0, stream>>>(y0, y32, dout);
  hipMemsetAsync(tmpH, 0, tmpH_bytes, stream);                  // zero halo ring (each call)
  init_transpose<<<2048, 256, 0, stream>>>(y0, tmpH);

  for (int step = 0; step < 24; ++step) {
    fused_stage<1><<<256, 512, 0, stream>>>(w1bf, w2bf, b1, b2, tmpH, y32, acc32, dout, tarr, step);
    fused_stage<2><<<256, 512, 0, stream>>>(w1bf, w2bf, b1, b2, tmpH, y32, acc32, dout, tarr, step);
    fused_stage<3><<<256, 512, 0, stream>>>(w1bf, w2bf, b1, b2, tmpH, y32, acc32, dout, tarr, step);
    fused_stage<4><<<256, 512, 0, stream>>>(w1bf, w2bf, b1, b2, tmpH, y32, acc32, dout, tarr, step);
  }
}

// Round 18
// 2300.659 us; speedup vs baseline: 2.0490x; 2.0490x over previous
//
#include <hip/hip_runtime.h>
#include <hip/hip_bf16.h>
#include <math.h>

typedef __attribute__((ext_vector_type(8))) short bf16x8;
typedef __attribute__((ext_vector_type(4))) float f32x4;
typedef __attribute__((ext_vector_type(4))) unsigned short u16x4;

#define B_   16
#define C_   128
#define CHW_ 131072   // 128*32*32
#define STR_ 138      // LDS pixel stride in shorts (69 dwords, odd -> bank spread)

__device__ __forceinline__ unsigned short f2bf(float f) {
  union { float f; unsigned int i; } v; v.f = f;
  unsigned int lsb = (v.i >> 16) & 1u;
  v.i += 0x7fffu + lsb;
  return (unsigned short)(v.i >> 16);
}

// fast tanh: 1 - 2/(e^{2x}+1). Saturates correctly at +/-inf.
__device__ __forceinline__ float fast_tanh(float x) {
  float e = __expf(2.f * x);
  return 1.f - 2.f * __builtin_amdgcn_rcpf(e + 1.f);
}

// ---- weight prep: W[O][I][3][3] f32 -> wpk[ks][co][ci&31] bf16, ks = off*4 + (ci>>5)
__global__ void prep_weights(const float* __restrict__ W1, const float* __restrict__ W2,
                             unsigned short* __restrict__ w1bf, unsigned short* __restrict__ w2bf) {
  int j = blockIdx.x * 256 + threadIdx.x;
  if (j >= 2 * 147456) return;
  int which = j / 147456;
  int r = j - which * 147456;
  int ks = r >> 12;
  int co = (r >> 5) & 127;
  int c5 = r & 31;
  int off = ks >> 2;
  int ci  = (ks & 3) * 32 + c5;
  const float* src = which ? W2 : W1;
  unsigned short* dst = which ? w2bf : w1bf;
  dst[r] = f2bf(src[(co * 128 + ci) * 9 + off]);
}

// ---- init: y32 = y0 (NCHW f32); dout[:,t=0,...] = y0
__global__ void init_copy(const float* __restrict__ y0, float* __restrict__ y32,
                          float* __restrict__ dout) {
  int i = blockIdx.x * 256 + threadIdx.x;
  if (i >= B_ * CHW_) return;
  float v = y0[i];
  y32[i] = v;
  int b = i >> 17, chw = i & (CHW_ - 1);
  dout[b * 25 * CHW_ + chw] = v;
}

// ---- init: tmp_bf (NHWC bf16) = transpose(y0)
__global__ void init_transpose(const float* __restrict__ y0, unsigned short* __restrict__ tmp_bf) {
  __shared__ float t[32][33];
  int blk = blockIdx.x;          // 16 b * 4 co-tiles * 32 pix-tiles = 2048
  int b = blk >> 7;
  int rem = blk & 127;
  int co0 = (rem >> 5) * 32;
  int p0  = (rem & 31) * 32;
  int tx = threadIdx.x & 31, ty = threadIdx.x >> 5;
  #pragma unroll
  for (int k = 0; k < 4; k++) {
    int cl = ty + k * 8;
    t[cl][tx] = y0[b * CHW_ + (co0 + cl) * 1024 + p0 + tx];
  }
  __syncthreads();
  #pragma unroll
  for (int k = 0; k < 4; k++) {
    int pl = ty + k * 8;
    tmp_bf[(b * 1024 + p0 + pl) * 128 + co0 + tx] = f2bf(t[tx][pl]);
  }
}

// ---- fused RK4 stage kernel (multi-launch, plain cached loads).
// r15 structure, with conv1 CONCENTRATED on waves 0-3 (each 32co = two 16-co
// fragments x 4 zrows x 32 cols): block conv1 LDS B-reads halve (1152->576 KB)
// while A traffic stays minimal (288 KB). Waves 4-7 prefetch their conv2
// epilogue state during conv1, then wait at the barrier.
// conv2 (all 8 waves): 16co x 2 rows x 32 cols, A-minimal (proven r15).
// Grid: 16 images x 16 rowpairs = 256 blocks (1/CU), 512 thr (8 waves).
template<int ST>
__global__ __launch_bounds__(512, 1)
void fused_stage(const unsigned short* __restrict__ w1bf,
                 const unsigned short* __restrict__ w2bf,
                 const float* __restrict__ b1v, const float* __restrict__ b2v,
                 unsigned short* __restrict__ tmp_bf,
                 float* __restrict__ y32, float* __restrict__ acc32,
                 float* __restrict__ dout, const float* __restrict__ tarr, int step)
{
  // IT: tmp tile, 6 rows (r0-2..r0+3) x 34 cols x 128 ci, pixel stride 138
  // ZT: z tile,   4 rows (r0-1..r0+2) x 34 cols x 128 co (LDS-only)
  __shared__ unsigned short IT[204 * STR_];
  __shared__ unsigned short ZT[136 * STR_];
  const int tid  = threadIdx.x;
  const int img  = blockIdx.x >> 4;
  const int r0   = (blockIdx.x & 15) * 2;
  const int lane = tid & 63;
  const int wave = tid >> 6;
  const int lhi  = lane >> 4;         // 0..3 (K octet / D row group)
  const int llo  = lane & 15;         // A: co row, B: sp col, D: col

  const unsigned short* a2base = w2bf + (wave * 16 + llo) * 32 + lhi * 8;

  float t0 = tarr[step];
  float t1 = tarr[step + 1];
  // keep one operand in a VGPR: avoids V_ADD_F32 with two SGPR sources
  // (constant-bus violation -> backend compile error on gfx950)
  asm volatile("" : "+v"(t1));
  const float dt = t1 - t0;
  const float dt6 = dt * (1.f / 6.f), dt3 = dt * (1.f / 3.f), dth = dt * 0.5f;

  // ---- stage tmp tile (6 rows, zero-padded halo) + zero ZT col pads
  for (int chunk = tid; chunk < 204 * 16 + 128; chunk += 512) {
    if (chunk < 204 * 16) {
      int pix = chunk >> 4;
      int oct = chunk & 15;
      int ir = pix / 34, ic = pix - ir * 34;
      int gr = r0 - 2 + ir, gc = ic - 1;
      bf16x8 v = {0, 0, 0, 0, 0, 0, 0, 0};
      if ((unsigned)gr < 32u && (unsigned)gc < 32u)
        v = *(const bf16x8*)(tmp_bf + ((img * 32 + gr) * 32 + gc) * 128 + oct * 8);
      *(bf16x8*)(IT + pix * STR_ + oct * 8) = v;
    } else {
      int padidx = chunk - 204 * 16;      // 0..127 : 4 zrows x 2 sides x 16 oct
      int zp  = padidx >> 4;
      int oct = padidx & 15;
      int zpix = (zp >> 1) * 34 + ((zp & 1) ? 33 : 0);
      bf16x8 z = {0, 0, 0, 0, 0, 0, 0, 0};
      *(bf16x8*)(ZT + zpix * STR_ + oct * 8) = z;
    }
  }
  __syncthreads();

  // conv2 epilogue state (prefetched: waves 4-7 during conv1, waves 0-3 after)
  const int co0 = wave * 16 + lhi * 4;
  float ypre[2][2][4], apre[2][2][4];
  auto prefetch_state = [&]() {
    #pragma unroll
    for (int q = 0; q < 2; ++q)
      #pragma unroll
      for (int spt = 0; spt < 2; ++spt) {
        const int idx0 = img * CHW_ + co0 * 1024 + (r0 + q) * 32 + spt * 16 + llo;
        #pragma unroll
        for (int reg = 0; reg < 4; ++reg) {
          if constexpr (ST <= 3) ypre[q][spt][reg] = y32[idx0 + reg * 1024];
          if constexpr (ST >= 2) apre[q][spt][reg] = acc32[idx0 + reg * 1024];
        }
      }
  };

  if (wave >= 4) {
    prefetch_state();   // idle during conv1: hide the strided scalar loads here
  } else {
    // ---- conv1: z = tanh(conv(tmp,W1)+b1); wave owns 32co x 4 zrows x 32 cols
    const int cob = wave * 32;
    const unsigned short* a1b = w1bf + (cob + llo) * 32 + lhi * 8;
    f32x4 bia[2];
    bia[0] = *(const f32x4*)(b1v + cob + lhi * 4);
    bia[1] = *(const f32x4*)(b1v + cob + 16 + lhi * 4);
    f32x4 a1[2][4][2];   // [ct][zr][spt]
    #pragma unroll
    for (int i = 0; i < 2; i++)
      #pragma unroll
      for (int j = 0; j < 4; j++) {
        a1[i][j][0] = (f32x4){0, 0, 0, 0};
        a1[i][j][1] = (f32x4){0, 0, 0, 0};
      }
    #pragma unroll
    for (int dw = 0; dw < 3; ++dw) {
      #pragma unroll
      for (int kk = 0; kk < 4; ++kk) {
        // 6 distinct input rows x 2 col-halves, shared across dh, zr AND both co-frags
        bf16x8 bfr[6][2];
        #pragma unroll
        for (int rr = 0; rr < 6; ++rr) {
          const int prow = rr * 34 + llo + dw;
          bfr[rr][0] = *(const bf16x8*)(IT + prow * STR_ + kk * 32 + lhi * 8);
          bfr[rr][1] = *(const bf16x8*)(IT + (prow + 16) * STR_ + kk * 32 + lhi * 8);
        }
        bf16x8 afr[2][3];
        #pragma unroll
        for (int dh = 0; dh < 3; ++dh) {
          const int ksoff = ((dh * 3 + dw) * 4 + kk) * 4096;
          afr[0][dh] = *(const bf16x8*)(a1b + ksoff);
          afr[1][dh] = *(const bf16x8*)(a1b + ksoff + 512);
        }
        #pragma unroll
        for (int dh = 0; dh < 3; ++dh)
          #pragma unroll
          for (int ct = 0; ct < 2; ++ct)
            #pragma unroll
            for (int zr = 0; zr < 4; ++zr)
              #pragma unroll
              for (int spt = 0; spt < 2; ++spt)
                a1[ct][zr][spt] = __builtin_amdgcn_mfma_f32_16x16x32_bf16(afr[ct][dh], bfr[zr + dh][spt], a1[ct][zr][spt], 0, 0, 0);
      }
    }
    #pragma unroll
    for (int ct = 0; ct < 2; ++ct) {
      const int co = cob + ct * 16 + lhi * 4;
      #pragma unroll
      for (int zr = 0; zr < 4; ++zr) {
        const bool live = (unsigned)(r0 - 1 + zr) < 32u;
        #pragma unroll
        for (int spt = 0; spt < 2; ++spt) {
          const int c = spt * 16 + llo;
          u16x4 pk;
          #pragma unroll
          for (int reg = 0; reg < 4; ++reg)
            pk[reg] = live ? f2bf(fast_tanh(a1[ct][zr][spt][reg] + bia[ct][reg])) : (unsigned short)0;
          *(u16x4*)(ZT + (zr * 34 + c + 1) * STR_ + co) = pk;
        }
      }
    }
  }
  __syncthreads();

  if (wave < 4) prefetch_state();

  // ---- conv2: k = conv(z,W2)+b2, wave computes 16co x 2 rows x 32 cols + RK4
  {
    f32x4 bia = *(const f32x4*)(b2v + co0);
    f32x4 a2[2][2];   // [q(row)][spt]
    #pragma unroll
    for (int i = 0; i < 2; i++) { a2[i][0] = (f32x4){0,0,0,0}; a2[i][1] = (f32x4){0,0,0,0}; }
    #pragma unroll
    for (int dw = 0; dw < 3; ++dw) {
      #pragma unroll
      for (int kk = 0; kk < 4; ++kk) {
        bf16x8 bfr[4][2];
        #pragma unroll
        for (int rr = 0; rr < 4; ++rr) {
          const int zpix = rr * 34 + llo + dw;
          bfr[rr][0] = *(const bf16x8*)(ZT + zpix * STR_ + kk * 32 + lhi * 8);
          bfr[rr][1] = *(const bf16x8*)(ZT + (zpix + 16) * STR_ + kk * 32 + lhi * 8);
        }
        bf16x8 afr[3];
        #pragma unroll
        for (int dh = 0; dh < 3; ++dh)
          afr[dh] = *(const bf16x8*)(a2base + ((dh * 3 + dw) * 4 + kk) * 4096);
        #pragma unroll
        for (int dh = 0; dh < 3; ++dh)
          #pragma unroll
          for (int q = 0; q < 2; ++q)
            #pragma unroll
            for (int spt = 0; spt < 2; ++spt)
              a2[q][spt] = __builtin_amdgcn_mfma_f32_16x16x32_bf16(afr[dh], bfr[q + dh][spt], a2[q][spt], 0, 0, 0);
      }
    }

    #pragma unroll
    for (int q = 0; q < 2; ++q) {
      const int row = r0 + q;
      #pragma unroll
      for (int spt = 0; spt < 2; ++spt) {
        const int col = spt * 16 + llo;
        const int pnhwc = (img * 1024 + row * 32 + col) * 128 + co0;
        const int idx0  = img * CHW_ + co0 * 1024 + row * 32 + col;
        u16x4 pk;
        #pragma unroll
        for (int reg = 0; reg < 4; ++reg) {
          float kv = a2[q][spt][reg] + bia[reg];
          int id = idx0 + reg * 1024;
          float tv;
          if constexpr (ST == 1)      { float yv = ypre[q][spt][reg]; acc32[id] = yv + dt6 * kv; tv = yv + dth * kv; }
          else if constexpr (ST == 2) { float yv = ypre[q][spt][reg]; acc32[id] = apre[q][spt][reg] + dt3 * kv; tv = yv + dth * kv; }
          else if constexpr (ST == 3) { float yv = ypre[q][spt][reg]; acc32[id] = apre[q][spt][reg] + dt3 * kv; tv = yv + dt * kv; }
          else {
            tv = apre[q][spt][reg] + dt6 * kv;
            y32[id] = tv;
            dout[(img * 25 + step + 1) * CHW_ + co0 * 1024 + row * 32 + col + reg * 1024] = tv;
          }
          pk[reg] = f2bf(tv);
        }
        *(u16x4*)(tmp_bf + pnhwc) = pk;
      }
    }
  }
}

extern "C" void kernel_launch(void* const* d_in, const int* in_sizes, int n_in,
                              void* d_out, int out_size, void* d_ws, size_t ws_size,
                              hipStream_t stream) {
  const float* y0   = (const float*)d_in[0];
  const float* tarr = (const float*)d_in[1];
  const float* W1   = (const float*)d_in[2];
  const float* b1   = (const float*)d_in[3];
  const float* W2   = (const float*)d_in[4];
  const float* b2   = (const float*)d_in[5];
  float* dout = (float*)d_out;

  char* ws = (char*)d_ws;
  float* y32             = (float*)(ws);                          // 8 MB (NCHW)
  float* acc32           = (float*)(ws + (8u << 20));             // 8 MB (NCHW)
  unsigned short* tmp_bf = (unsigned short*)(ws + (16u << 20));   // 4 MB (NHWC)
  unsigned short* w1bf   = (unsigned short*)(ws + (20u << 20));   // 288 KB
  unsigned short* w2bf   = (unsigned short*)(ws + (20u << 20) + 294912);

  prep_weights<<<(2 * 147456 + 255) / 256, 256, 0, stream>>>(W1, W2, w1bf, w2bf);
  init_copy<<<(B_ * CHW_ + 255) / 256, 256, 0, stream>>>(y0, y32, dout);
  init_transpose<<<2048, 256, 0, stream>>>(y0, tmp_bf);

  for (int step = 0; step < 24; ++step) {
    fused_stage<1><<<256, 512, 0, stream>>>(w1bf, w2bf, b1, b2, tmp_bf, y32, acc32, dout, tarr, step);
    fused_stage<2><<<256, 512, 0, stream>>>(w1bf, w2bf, b1, b2, tmp_bf, y32, acc32, dout, tarr, step);
    fused_stage<3><<<256, 512, 0, stream>>>(w1bf, w2bf, b1, b2, tmp_bf, y32, acc32, dout, tarr, step);
    fused_stage<4><<<256, 512, 0, stream>>>(w1bf, w2bf, b1, b2, tmp_bf, y32, acc32, dout, tarr, step);
  }
}